// Round 18
// baseline (407.027 us; speedup 1.0000x reference)
//
#include <hip/hip_runtime.h>

#define NN 100000
#define EE 1600000
#define DD 128
#define FFD 512
#define EPSV 1e-5f

#define SCB 98      // scan blocks: ceil(100000/1024)
#define EB 6250     // edge blocks in k_pre
#define MIXB 18750  // EB*3 (1 edge : 2 xb interleave)

typedef __attribute__((ext_vector_type(8))) short bf16x8;
typedef __attribute__((ext_vector_type(4))) float f32x4;
typedef unsigned long long ull;

__device__ __forceinline__ ushort f2b(float f) {          // fp32 -> bf16 RNE
    uint u = __float_as_uint(f);
    return (ushort)((u + 0x7FFF + ((u >> 16) & 1)) >> 16);
}
__device__ __forceinline__ float b2f(ushort u) {
    return __uint_as_float(((uint)u) << 16);
}

// async 16B global->LDS copy (linear dest; vmcnt-drained by __syncthreads)
__device__ __forceinline__ void gld_lds16(const ushort* g, ushort* l) {
    __builtin_amdgcn_global_load_lds(
        (const __attribute__((address_space(1))) uint*)g,
        (__attribute__((address_space(3))) uint*)l, 16, 0, 0);
}

// ---------------- init: pk=0, stats=0 ----------------

__global__ __launch_bounds__(256) void k_init(ull* pk, float* s1, float* s2) {
    int i = blockIdx.x * 256 + threadIdx.x;
    if (i < NN) pk[i] = 0ULL;
    if (blockIdx.x == 0) { s1[threadIdx.x] = 0.f; s2[threadIdx.x] = 0.f; }
}

// ---------------- fused pre-pass: edge_deg (atomics) || x->bf16 || weight images ----------------

__global__ __launch_bounds__(256) void k_pre(const int* __restrict__ ei,
                                             const float* __restrict__ ew,
                                             ull* __restrict__ pk,
                                             int* __restrict__ rank,
                                             const float* __restrict__ x,
                                             ushort* __restrict__ xb,
                                             const float* __restrict__ W,
                                             const float* __restrict__ W1,
                                             const float* __restrict__ W2,
                                             ushort* __restrict__ WTimg,
                                             ushort* __restrict__ W1img,
                                             ushort* __restrict__ W2img) {
    int bid = blockIdx.x;
    int t = threadIdx.x;
    if (bid < MIXB) {
        if (bid % 3 == 0) {
            int e = (bid / 3) * 256 + t;   // EB*256 == EE exactly
            int dst = ei[EE + e];
            uint fx = (uint)(ew[e] * 16777216.0f + 0.5f);
            ull old = atomicAdd(&pk[dst], (1ULL << 32) | (ull)fx);
            rank[e] = (int)(old >> 32);
        } else {
            int xbk = bid - bid / 3 - 1;   // 0..12499
            long i = (long)xbk * 256 + t;
            float4 v = ((const float4*)x)[i];
            ushort4 o;
            o.x = f2b(v.x); o.y = f2b(v.y); o.z = f2b(v.z); o.w = f2b(v.w);
            ((ushort4*)xb)[i] = o;
        }
    } else {
        int i = (bid - MIXB) * 256 + t;
        if (i < 16384) {
            // WTimg: swizzled image of W^T (row n = out feature, col = k slot)
            int n = i >> 7, col = i & 127;
            int k = ((((col >> 3) ^ (n & 15)) << 3)) + (col & 7);
            WTimg[i] = f2b(W[k * 128 + n]);
        } else if (i < 16384 + 65536) {
            // W1img: per-chunk swizzled [f_local][k] image
            int u = i - 16384;
            int ch = u >> 14, rem = u & 16383;
            int f = rem >> 7, col = rem & 127;
            int kb = (col >> 3) ^ (f & 15);
            int j = col & 7;
            W1img[u] = f2b(W1[(kb * 8 + j) * 512 + ch * 128 + f]);
        } else {
            // W2img: per-chunk swizzled [j_row][f_local] image
            int u = i - 16384 - 65536;
            int ch = u >> 14, rem = u & 16383;
            int jrow = rem >> 7, col = rem & 127;
            int kb = (col >> 3) ^ (jrow & 15);
            int j2 = col & 7;
            W2img[u] = f2b(W2[(ch * 128 + kb * 8 + j2) * 128 + jrow]);
        }
    }
}

// ---------------- scan part 1: block sums; unpack pk -> cnt, dinv ----------------

__global__ __launch_bounds__(256) void k_scan_part(const ull* __restrict__ pk,
                                                   int* __restrict__ cnt,
                                                   float* __restrict__ dinv,
                                                   int* __restrict__ bsum) {
    __shared__ int red[4];
    int b = blockIdx.x, t = threadIdx.x;
    int base = b * 1024 + t * 4;
    int s = 0;
#pragma unroll
    for (int j = 0; j < 4; ++j) {
        int i = base + j;
        if (i < NN) {
            ull v = pk[i];
            int c = (int)(v >> 32);
            cnt[i] = c;
            dinv[i] = rsqrtf(1.0f + (float)(uint)(v & 0xFFFFFFFFu) * (1.0f / 16777216.0f));
            s += c;
        }
    }
#pragma unroll
    for (int d = 1; d < 64; d <<= 1) s += __shfl_xor(s, d);
    if ((t & 63) == 0) red[t >> 6] = s;
    __syncthreads();
    if (t == 0) bsum[b] = red[0] + red[1] + red[2] + red[3];
}

__global__ __launch_bounds__(128) void k_scan_base(int* __restrict__ bsum,
                                                   int* __restrict__ bbase,
                                                   int* __restrict__ start) {
    if (threadIdx.x == 0) {
        int run = 0;
        for (int i = 0; i < SCB; ++i) { bbase[i] = run; run += bsum[i]; }
        start[NN] = run;   // == EE
    }
}

__global__ __launch_bounds__(256) void k_scan_fin(const int* __restrict__ cnt,
                                                  const int* __restrict__ bbase,
                                                  int* __restrict__ start) {
    __shared__ int ts[256];
    int b = blockIdx.x, t = threadIdx.x;
    int base = b * 1024 + t * 4;
    int v[4];
    int s = 0;
#pragma unroll
    for (int j = 0; j < 4; ++j) {
        int i = base + j;
        v[j] = (i < NN) ? cnt[i] : 0;
        s += v[j];
    }
    ts[t] = s;
    __syncthreads();
    for (int d = 1; d < 256; d <<= 1) {
        int add = (t >= d) ? ts[t - d] : 0;
        __syncthreads();
        ts[t] += add;
        __syncthreads();
    }
    int run = bbase[b] + ts[t] - s;   // exclusive offset for this thread
#pragma unroll
    for (int j = 0; j < 4; ++j) {
        int i = base + j;
        if (i < NN) {
            start[i] = run;
            run += v[j];
        }
    }
}

// ---------------- fill CSR records (src, norm), ATOMIC-FREE via rank ----------------

__global__ __launch_bounds__(256) void k_fill(const int* __restrict__ ei,
                                              const float* __restrict__ ew,
                                              const float* __restrict__ dinv,
                                              const int* __restrict__ start,
                                              const int* __restrict__ rank,
                                              uint2* __restrict__ csr) {
    int e = blockIdx.x * 256 + threadIdx.x;
    if (e < EE) {
        int src = ei[e];
        int dst = ei[EE + e];
        float nrm = dinv[src] * ew[e] * dinv[dst];
        int pos = start[dst] + rank[e];
        csr[pos] = make_uint2((uint)src, __float_as_uint(nrm));
    }
}

// ---------------- fused gather + conv GEMM ----------------
// 64 nodes/block, 8 waves. Gather phase streams each wave's CONTIGUOUS csr range
// [start[n0], start[n0+8]) with a boundary-flush accumulator (pipeline never drains).
// Then y = x~ + agg @ W + b -> ybuf (bf16), BN1 stats. W async-staged from WTimg.

#define SWZ16(row, kb) ((((kb) ^ ((row) & 15)) << 3))

__global__ __launch_bounds__(512, 6) void k_gconv(const ushort* __restrict__ xb,
                                                  const float* __restrict__ dinv,
                                                  const int* __restrict__ start,
                                                  const uint2* __restrict__ csr,
                                                  const ushort* __restrict__ WTimg,
                                                  const float* __restrict__ b,
                                                  ushort* __restrict__ ybuf,
                                                  float* __restrict__ stats1) {
    __shared__ __align__(16) ushort xt[64 * 128];   // 16 KB agg tile (swizzled)
    __shared__ __align__(16) ushort wc[128 * 128];  // 32 KB W image
    int t = threadIdx.x;
    int row0 = blockIdx.x * 64;   // grid 1563; last block partial
    int wv = t >> 6, l = t & 63;

    // async stage W image (linear 32KB)
#pragma unroll
    for (int i = 0; i < 4; ++i) {
        int u = (t + i * 512) * 8;
        gld_lds16(WTimg + u, wc + u);
    }

    // streaming gather: 8 nodes per wave, contiguous csr range, boundary-flush
    const uint* xbu = (const uint*)xb;
    {
        int nbase0 = wv * 8;          // local row base
        int nb0 = row0 + nbase0;      // global node base
        int c0 = nb0 < NN ? nb0 : NN;
        int c8 = (nb0 + 8) < NN ? (nb0 + 8) : NN;
        int E0 = start[c0];
        int E8 = start[c8];
        int cur = 0;
        int ni = (nb0 + 1) < NN ? (nb0 + 1) : NN;
        int bnd_next = start[ni];
        float a0 = 0.f, a1 = 0.f;

        auto flush = [&]() {
            int node = nb0 + cur;
            if (node < NN) {
                float dv = dinv[node];
                float sl = dv * dv;
                uint hs = xbu[(long)node * 64 + l];
                a0 = fmaf(sl, b2f((ushort)(hs & 0xFFFF)), a0);
                a1 = fmaf(sl, b2f((ushort)(hs >> 16)), a1);
            }
            int rloc = nbase0 + cur;
            int col = 2 * l;
            *(uint*)&xt[rloc * 128 + SWZ16(rloc, col >> 3) + (col & 7)] =
                (uint)f2b(a0) | ((uint)f2b(a1) << 16);
            a0 = 0.f; a1 = 0.f;
            ++cur;
            int nxt = (nb0 + cur + 1) < NN ? (nb0 + cur + 1) : NN;
            bnd_next = start[nxt];
        };

        for (int i = E0; i < E8; i += 8) {
            uint2 rr[8];
            uint hh[8];
            int rem = E8 - i;
#pragma unroll
            for (int u = 0; u < 8; ++u)
                rr[u] = (u < rem) ? csr[i + u] : make_uint2(0u, 0u);
#pragma unroll
            for (int u = 0; u < 8; ++u) hh[u] = xbu[rr[u].x * 64 + l];
#pragma unroll
            for (int u = 0; u < 8; ++u) {
                while (cur < 8 && i + u >= bnd_next) flush();
                float n = __uint_as_float(rr[u].y);
                a0 = fmaf(n, b2f((ushort)(hh[u] & 0xFFFF)), a0);
                a1 = fmaf(n, b2f((ushort)(hh[u] >> 16)), a1);
            }
        }
        while (cur < 8) flush();
    }
    __syncthreads();   // xt complete; gld_lds drained -> wc ready

    int lr = l & 15, lg = l >> 4;
    int rw = wv & 3, jw = wv >> 2;
    int xrow = rw * 16 + lr;

    f32x4 z4 = {0.f, 0.f, 0.f, 0.f};
    f32x4 acc[4];
#pragma unroll
    for (int jt = 0; jt < 4; ++jt) acc[jt] = z4;

#pragma unroll
    for (int ks = 0; ks < 4; ++ks) {
        int kcol = ((ks * 4 + lg) ^ lr) << 3;
        bf16x8 qR = *(const bf16x8*)&xt[xrow * 128 + kcol];
#pragma unroll
        for (int jt = 0; jt < 4; ++jt) {
            int f = jw * 64 + jt * 16 + lr;
            bf16x8 pW = *(const bf16x8*)&wc[f * 128 + kcol];
            acc[jt] = __builtin_amdgcn_mfma_f32_16x16x32_bf16(pW, qR, acc[jt], 0, 0, 0);
        }
    }

    // epilogue: y = x~ + acc + b -> ybuf (bf16), BN1 partials
    float sj[4][4], qj[4][4];
    int r = row0 + xrow;
#pragma unroll
    for (int jt = 0; jt < 4; ++jt) {
        int jb = jw * 64 + jt * 16 + lg * 4;
        float4 bv = *(const float4*)&b[jb];
        if (r < NN) {
            ushort4 xv = *(const ushort4*)&xb[(long)r * 128 + jb];
            float z0 = b2f(xv.x) + acc[jt][0] + bv.x;
            float z1 = b2f(xv.y) + acc[jt][1] + bv.y;
            float z2 = b2f(xv.z) + acc[jt][2] + bv.z;
            float z3 = b2f(xv.w) + acc[jt][3] + bv.w;
            ushort4 o;
            o.x = f2b(z0); o.y = f2b(z1); o.z = f2b(z2); o.w = f2b(z3);
            *(ushort4*)&ybuf[(long)r * 128 + jb] = o;
            sj[jt][0] = z0; sj[jt][1] = z1; sj[jt][2] = z2; sj[jt][3] = z3;
            qj[jt][0] = z0 * z0; qj[jt][1] = z1 * z1; qj[jt][2] = z2 * z2; qj[jt][3] = z3 * z3;
        } else {
            sj[jt][0] = 0.f; sj[jt][1] = 0.f; sj[jt][2] = 0.f; sj[jt][3] = 0.f;
            qj[jt][0] = 0.f; qj[jt][1] = 0.f; qj[jt][2] = 0.f; qj[jt][3] = 0.f;
        }
    }
#pragma unroll
    for (int jt = 0; jt < 4; ++jt)
#pragma unroll
        for (int g = 0; g < 4; ++g) {
#pragma unroll
            for (int d = 1; d < 16; d <<= 1) {
                sj[jt][g] += __shfl_xor(sj[jt][g], d);
                qj[jt][g] += __shfl_xor(qj[jt][g], d);
            }
        }
    __syncthreads();   // xt reads done; reuse as reduction buffer
    float* redS = (float*)&xt[0];    // [8][128]
    float* redQ = redS + 1024;       // [8][128]
    if (lr == 0) {
#pragma unroll
        for (int jt = 0; jt < 4; ++jt)
#pragma unroll
            for (int g = 0; g < 4; ++g) {
                int j = jw * 64 + jt * 16 + lg * 4 + g;
                redS[wv * 128 + j] = sj[jt][g];
                redQ[wv * 128 + j] = qj[jt][g];
            }
    }
    __syncthreads();
    if (t < 128) {
        int h = t >> 6;   // j-half; owned by waves h*4 .. h*4+3
        float S = redS[(h * 4 + 0) * 128 + t] + redS[(h * 4 + 1) * 128 + t]
                + redS[(h * 4 + 2) * 128 + t] + redS[(h * 4 + 3) * 128 + t];
        float Q = redQ[(h * 4 + 0) * 128 + t] + redQ[(h * 4 + 1) * 128 + t]
                + redQ[(h * 4 + 2) * 128 + t] + redQ[(h * 4 + 3) * 128 + t];
        atomicAdd(&stats1[t], S);
        atomicAdd(&stats1[128 + t], Q);
    }
}

// ---------------- BN finalize ----------------

__global__ __launch_bounds__(128) void k_bn_fin(const float* __restrict__ stats,
                                                const float* __restrict__ gamma,
                                                const float* __restrict__ beta,
                                                float* __restrict__ ac) {
    int c = threadIdx.x;
    float mu = stats[c] * (1.0f / NN);
    float var = stats[128 + c] * (1.0f / NN) - mu * mu;
    float a = gamma[c] * rsqrtf(var + EPSV);
    ac[c] = a;
    ac[128 + c] = beta[c] - mu * a;
}

// ---------------- final affine: out = a * zb + c (bf16 in, fp32 out) ----------------

__global__ __launch_bounds__(256) void k_affine2(const ushort* __restrict__ zb,
                                                 const float* __restrict__ ac,
                                                 float* __restrict__ out) {
    long i = (long)blockIdx.x * 256 + threadIdx.x;   // float4 units
    int c4i = (int)(i & 31);
    float4 a = ((const float4*)ac)[c4i];
    float4 cc = ((const float4*)(ac + 128))[c4i];
    ushort4 zv = ((const ushort4*)zb)[i];
    float4 o;
    o.x = a.x * b2f(zv.x) + cc.x;
    o.y = a.y * b2f(zv.y) + cc.y;
    o.z = a.z * b2f(zv.z) + cc.z;
    o.w = a.w * b2f(zv.w) + cc.w;
    ((float4*)out)[i] = o;
}

// ---------------- fused MLP v10: async image staging + swapped GEMM1 ----------------

__global__ __launch_bounds__(512, 4) void k_mlp(const ushort* __restrict__ yb,
                                                const float* __restrict__ ac1,
                                                const ushort* __restrict__ W1img,
                                                const float* __restrict__ b1,
                                                const ushort* __restrict__ W2img,
                                                const float* __restrict__ b2,
                                                ushort* __restrict__ zb,
                                                float* __restrict__ stats2) {
    __shared__ __align__(16) ushort xt[64 * 128];   // 16 KB
    __shared__ __align__(16) ushort ht[64 * 128];   // 16 KB
    __shared__ __align__(16) ushort wc[128 * 128];  // 32 KB
    int t = threadIdx.x;
    int row0 = blockIdx.x * 64;   // grid 1563; last block partial

    // stage x1 = affine(yb) -> bf16, swizzled (1024 x 16B)
    for (int i = t; i < 1024; i += 512) {
        int r = i >> 4, kb = i & 15;
        int gr = row0 + r;
        ushort4 y0 = make_ushort4(0, 0, 0, 0), y1 = make_ushort4(0, 0, 0, 0);
        if (gr < NN) {
            long base = (long)gr * 32 + kb * 2;
            y0 = ((const ushort4*)yb)[base];
            y1 = ((const ushort4*)yb)[base + 1];
        }
        float4 a0 = ((const float4*)ac1)[kb * 2];
        float4 a1 = ((const float4*)ac1)[kb * 2 + 1];
        float4 c0 = ((const float4*)(ac1 + 128))[kb * 2];
        float4 c1 = ((const float4*)(ac1 + 128))[kb * 2 + 1];
        ushort4 o0, o1;
        o0.x = f2b(a0.x * b2f(y0.x) + c0.x);
        o0.y = f2b(a0.y * b2f(y0.y) + c0.y);
        o0.z = f2b(a0.z * b2f(y0.z) + c0.z);
        o0.w = f2b(a0.w * b2f(y0.w) + c0.w);
        o1.x = f2b(a1.x * b2f(y1.x) + c1.x);
        o1.y = f2b(a1.y * b2f(y1.y) + c1.y);
        o1.z = f2b(a1.z * b2f(y1.z) + c1.z);
        o1.w = f2b(a1.w * b2f(y1.w) + c1.w);
        ushort* dst = &xt[r * 128 + SWZ16(r, kb)];
        *(ushort4*)dst = o0;
        *(ushort4*)(dst + 4) = o1;
    }

    int wv = t >> 6, l = t & 63;
    int lr = l & 15, lg = l >> 4;
    int rw = wv & 3, jw = wv >> 2;
    int xrow = rw * 16 + lr;        // xrow & 15 == lr

    f32x4 z4 = {0.f, 0.f, 0.f, 0.f};
    f32x4 acc[4];
#pragma unroll
    for (int jt = 0; jt < 4; ++jt) acc[jt] = z4;

    for (int ch = 0; ch < 4; ++ch) {
        __syncthreads();   // wc free (prev GEMM2 done); xt staged (ch=0)
        {
            const ushort* src = W1img + ch * 16384;
#pragma unroll
            for (int i = 0; i < 4; ++i) {
                int u = (t + i * 512) * 8;
                gld_lds16(src + u, wc + u);
            }
        }
        __syncthreads();   // drains vmcnt -> wc = W1ch ready

        // GEMM1 SWAPPED: hacc[ft] holds 4 consecutive f per reg, col = xrow
        f32x4 hacc[4];
#pragma unroll
        for (int ft = 0; ft < 4; ++ft) hacc[ft] = z4;
#pragma unroll
        for (int ks = 0; ks < 4; ++ks) {
            int kcol = ((ks * 4 + lg) ^ lr) << 3;
            bf16x8 aR = *(const bf16x8*)&xt[xrow * 128 + kcol];
#pragma unroll
            for (int ft = 0; ft < 4; ++ft) {
                int f = jw * 64 + ft * 16 + lr;
                bf16x8 bW = *(const bf16x8*)&wc[f * 128 + kcol];
                hacc[ft] = __builtin_amdgcn_mfma_f32_16x16x32_bf16(bW, aR, hacc[ft], 0, 0, 0);
            }
        }
#pragma unroll
        for (int ft = 0; ft < 4; ++ft) {
            int fc = jw * 64 + ft * 16 + lg * 4;
            float4 b1v = *(const float4*)&b1[ch * 128 + fc];
            ushort4 o;
            o.x = f2b(fmaxf(hacc[ft][0] + b1v.x, 0.f));
            o.y = f2b(fmaxf(hacc[ft][1] + b1v.y, 0.f));
            o.z = f2b(fmaxf(hacc[ft][2] + b1v.z, 0.f));
            o.w = f2b(fmaxf(hacc[ft][3] + b1v.w, 0.f));
            *(ushort4*)&ht[xrow * 128 + (((fc >> 3) ^ lr) << 3) + (fc & 7)] = o;
        }
        __syncthreads();   // ht complete, wc free

        {
            const ushort* src = W2img + ch * 16384;
#pragma unroll
            for (int i = 0; i < 4; ++i) {
                int u = (t + i * 512) * 8;
                gld_lds16(src + u, wc + u);
            }
        }
        __syncthreads();   // drains vmcnt -> wc = W2ch ready

        // GEMM2 swapped: acc(j x r) += W2c-rows x ht-rows
#pragma unroll
        for (int ks = 0; ks < 4; ++ks) {
            int kcol = ((ks * 4 + lg) ^ lr) << 3;
            bf16x8 qR = *(const bf16x8*)&ht[xrow * 128 + kcol];
#pragma unroll
            for (int jt = 0; jt < 4; ++jt) {
                int j = jw * 64 + jt * 16 + lr;
                bf16x8 pW = *(const bf16x8*)&wc[j * 128 + kcol];
                acc[jt] = __builtin_amdgcn_mfma_f32_16x16x32_bf16(pW, qR, acc[jt], 0, 0, 0);
            }
        }
    }

    // epilogue: z = x1 + x2 + b2 -> zb (bf16), BN2 partials
    float sj[4][4], qj[4][4];
    int r = row0 + xrow;
#pragma unroll
    for (int jt = 0; jt < 4; ++jt) {
        int jb = jw * 64 + jt * 16 + lg * 4;
        float4 b2v = *(const float4*)&b2[jb];
        int kbj = jb >> 3, wj = jb & 7;
        ushort4 xv = *(const ushort4*)&xt[xrow * 128 + ((kbj ^ lr) << 3) + wj];
        float z0 = b2f(xv.x) + acc[jt][0] + b2v.x;
        float z1 = b2f(xv.y) + acc[jt][1] + b2v.y;
        float z2 = b2f(xv.z) + acc[jt][2] + b2v.z;
        float z3 = b2f(xv.w) + acc[jt][3] + b2v.w;
        if (r < NN) {
            ushort4 o;
            o.x = f2b(z0); o.y = f2b(z1); o.z = f2b(z2); o.w = f2b(z3);
            *(ushort4*)&zb[(long)r * 128 + jb] = o;
            sj[jt][0] = z0; sj[jt][1] = z1; sj[jt][2] = z2; sj[jt][3] = z3;
            qj[jt][0] = z0 * z0; qj[jt][1] = z1 * z1; qj[jt][2] = z2 * z2; qj[jt][3] = z3 * z3;
        } else {
            sj[jt][0] = 0.f; sj[jt][1] = 0.f; sj[jt][2] = 0.f; sj[jt][3] = 0.f;
            qj[jt][0] = 0.f; qj[jt][1] = 0.f; qj[jt][2] = 0.f; qj[jt][3] = 0.f;
        }
    }
#pragma unroll
    for (int jt = 0; jt < 4; ++jt)
#pragma unroll
        for (int g = 0; g < 4; ++g) {
#pragma unroll
            for (int d = 1; d < 16; d <<= 1) {
                sj[jt][g] += __shfl_xor(sj[jt][g], d);
                qj[jt][g] += __shfl_xor(qj[jt][g], d);
            }
        }
    __syncthreads();   // ht reads done; reuse as reduction buffer
    float* redS = (float*)&ht[0];    // [8][128]
    float* redQ = redS + 1024;       // [8][128]
    if (lr == 0) {
#pragma unroll
        for (int jt = 0; jt < 4; ++jt)
#pragma unroll
            for (int g = 0; g < 4; ++g) {
                int j = jw * 64 + jt * 16 + lg * 4 + g;
                redS[wv * 128 + j] = sj[jt][g];
                redQ[wv * 128 + j] = qj[jt][g];
            }
    }
    __syncthreads();
    if (t < 128) {
        int h = t >> 6;   // j-half; owned by waves h*4 .. h*4+3
        float S = redS[(h * 4 + 0) * 128 + t] + redS[(h * 4 + 1) * 128 + t]
                + redS[(h * 4 + 2) * 128 + t] + redS[(h * 4 + 3) * 128 + t];
        float Q = redQ[(h * 4 + 0) * 128 + t] + redQ[(h * 4 + 1) * 128 + t]
                + redQ[(h * 4 + 2) * 128 + t] + redQ[(h * 4 + 3) * 128 + t];
        atomicAdd(&stats2[t], S);
        atomicAdd(&stats2[128 + t], Q);
    }
}

// ---------------- launch ----------------

extern "C" void kernel_launch(void* const* d_in, const int* in_sizes, int n_in,
                              void* d_out, int out_size, void* d_ws, size_t ws_size,
                              hipStream_t stream) {
    const float* x     = (const float*)d_in[0];
    const int*   ei    = (const int*)d_in[1];
    const float* ew    = (const float*)d_in[2];
    const float* W     = (const float*)d_in[3];
    const float* b     = (const float*)d_in[4];
    const float* gamma = (const float*)d_in[5];
    const float* beta  = (const float*)d_in[6];
    const float* W1    = (const float*)d_in[7];
    const float* b1    = (const float*)d_in[8];
    const float* W2    = (const float*)d_in[9];
    const float* b2    = (const float*)d_in[10];
    float* out = (float*)d_out;
    float* ws  = (float*)d_ws;

    ull*   pk     = (ull*)ws;                        // NN (8B each)
    float* dinv   = ws + 2 * NN;                     // NN
    float* stats1 = ws + 3 * NN;                     // 256
    float* ac1    = stats1 + 256;                    // 256
    float* stats2 = ac1 + 256;                       // 256
    float* ac2    = stats2 + 256;                    // 256
    ushort* xb    = (ushort*)(ws + 3 * NN + 1024);   // NN*128 bf16
    ushort* WTimg = xb + (long)NN * 128;             // 16384
    ushort* W1img = WTimg + 16384;                   // 65536
    ushort* W2img = W1img + 65536;                   // 65536
    float*  fend  = ws + 3 * NN + 1024 + (long)NN * 64 + 73728;
    int*   cnt    = (int*)fend;                      // NN
    int*   start  = cnt + NN;                        // NN+1
    int*   bsum   = start + NN + 1;                  // SCB
    int*   bbase  = bsum + SCB;                      // SCB
    uint2* csr    = (uint2*)(((uintptr_t)(bbase + SCB) + 7) & ~(uintptr_t)7);  // EE records
    ushort* ybuf  = (ushort*)(csr + EE);             // NN*128 bf16 (y)
    int*   rank   = (int*)ybuf;                      // EE ints; lifetime before ybuf (disjoint)
    ushort* zb    = xb;                              // xb dead after k_gconv; reuse for bf16 z

    int nb = (NN + 63) / 64;   // 1563

    k_init<<<(NN + 255) / 256, 256, 0, stream>>>(pk, stats1, stats2);
    k_pre<<<MIXB + 576, 256, 0, stream>>>(ei, ew, pk, rank, x, xb, W, W1, W2, WTimg, W1img, W2img);
    k_scan_part<<<SCB, 256, 0, stream>>>(pk, cnt, dinv, bsum);
    k_scan_base<<<1, 128, 0, stream>>>(bsum, bbase, start);
    k_scan_fin<<<SCB, 256, 0, stream>>>(cnt, bbase, start);
    k_fill<<<EE / 256, 256, 0, stream>>>(ei, ew, dinv, start, rank, csr);
    k_gconv<<<nb, 512, 0, stream>>>(xb, dinv, start, csr, WTimg, b, ybuf, stats1);
    k_bn_fin<<<1, 128, 0, stream>>>(stats1, gamma, beta, ac1);
    k_mlp<<<nb, 512, 0, stream>>>(ybuf, ac1, W1img, b1, W2img, b2, zb, stats2);
    k_bn_fin<<<1, 128, 0, stream>>>(stats2, gamma, beta, ac2);
    k_affine2<<<(NN * 32) / 256, 256, 0, stream>>>(zb, ac2, out);
}

// Round 19
// 347.179 us; speedup vs baseline: 1.1724x; 1.1724x over previous
//
#include <hip/hip_runtime.h>

#define NN 100000
#define EE 1600000
#define DD 128
#define FFD 512
#define EPSV 1e-5f

#define SCB 98      // scan blocks: ceil(100000/1024)
#define EB 6250     // edge blocks in k_pre
#define MIXB 18750  // EB*3 (1 edge : 2 xb interleave)

typedef __attribute__((ext_vector_type(8))) short bf16x8;
typedef __attribute__((ext_vector_type(4))) float f32x4;
typedef unsigned long long ull;

__device__ __forceinline__ ushort f2b(float f) {          // fp32 -> bf16 RNE
    uint u = __float_as_uint(f);
    return (ushort)((u + 0x7FFF + ((u >> 16) & 1)) >> 16);
}
__device__ __forceinline__ float b2f(ushort u) {
    return __uint_as_float(((uint)u) << 16);
}

// async 16B global->LDS copy (linear dest; vmcnt-drained by __syncthreads)
__device__ __forceinline__ void gld_lds16(const ushort* g, ushort* l) {
    __builtin_amdgcn_global_load_lds(
        (const __attribute__((address_space(1))) uint*)g,
        (__attribute__((address_space(3))) uint*)l, 16, 0, 0);
}

// ---------------- init: pk=0, stats=0 ----------------

__global__ __launch_bounds__(256) void k_init(ull* pk, float* s1, float* s2) {
    int i = blockIdx.x * 256 + threadIdx.x;
    if (i < NN) pk[i] = 0ULL;
    if (blockIdx.x == 0) { s1[threadIdx.x] = 0.f; s2[threadIdx.x] = 0.f; }
}

// ---------------- fused pre-pass: edge_deg (atomics) || x->bf16 || weight images ----------------

__global__ __launch_bounds__(256) void k_pre(const int* __restrict__ ei,
                                             const float* __restrict__ ew,
                                             ull* __restrict__ pk,
                                             int* __restrict__ rank,
                                             const float* __restrict__ x,
                                             ushort* __restrict__ xb,
                                             const float* __restrict__ W,
                                             const float* __restrict__ W1,
                                             const float* __restrict__ W2,
                                             ushort* __restrict__ WTimg,
                                             ushort* __restrict__ W1img,
                                             ushort* __restrict__ W2img) {
    int bid = blockIdx.x;
    int t = threadIdx.x;
    if (bid < MIXB) {
        if (bid % 3 == 0) {
            int e = (bid / 3) * 256 + t;   // EB*256 == EE exactly
            int dst = ei[EE + e];
            uint fx = (uint)(ew[e] * 16777216.0f + 0.5f);
            ull old = atomicAdd(&pk[dst], (1ULL << 32) | (ull)fx);
            rank[e] = (int)(old >> 32);
        } else {
            int xbk = bid - bid / 3 - 1;   // 0..12499
            long i = (long)xbk * 256 + t;
            float4 v = ((const float4*)x)[i];
            ushort4 o;
            o.x = f2b(v.x); o.y = f2b(v.y); o.z = f2b(v.z); o.w = f2b(v.w);
            ((ushort4*)xb)[i] = o;
        }
    } else {
        int i = (bid - MIXB) * 256 + t;
        if (i < 16384) {
            // WTimg: swizzled image of W^T (row n = out feature, col = k slot)
            int n = i >> 7, col = i & 127;
            int k = ((((col >> 3) ^ (n & 15)) << 3)) + (col & 7);
            WTimg[i] = f2b(W[k * 128 + n]);
        } else if (i < 16384 + 65536) {
            // W1img: per-chunk swizzled [f_local][k] image
            int u = i - 16384;
            int ch = u >> 14, rem = u & 16383;
            int f = rem >> 7, col = rem & 127;
            int kb = (col >> 3) ^ (f & 15);
            int j = col & 7;
            W1img[u] = f2b(W1[(kb * 8 + j) * 512 + ch * 128 + f]);
        } else {
            // W2img: per-chunk swizzled [j_row][f_local] image
            int u = i - 16384 - 65536;
            int ch = u >> 14, rem = u & 16383;
            int jrow = rem >> 7, col = rem & 127;
            int kb = (col >> 3) ^ (jrow & 15);
            int j2 = col & 7;
            W2img[u] = f2b(W2[(ch * 128 + kb * 8 + j2) * 128 + jrow]);
        }
    }
}

// ---------------- scan part 1: block sums; unpack pk -> cnt, dinv ----------------

__global__ __launch_bounds__(256) void k_scan_part(const ull* __restrict__ pk,
                                                   int* __restrict__ cnt,
                                                   float* __restrict__ dinv,
                                                   int* __restrict__ bsum) {
    __shared__ int red[4];
    int b = blockIdx.x, t = threadIdx.x;
    int base = b * 1024 + t * 4;
    int s = 0;
#pragma unroll
    for (int j = 0; j < 4; ++j) {
        int i = base + j;
        if (i < NN) {
            ull v = pk[i];
            int c = (int)(v >> 32);
            cnt[i] = c;
            dinv[i] = rsqrtf(1.0f + (float)(uint)(v & 0xFFFFFFFFu) * (1.0f / 16777216.0f));
            s += c;
        }
    }
#pragma unroll
    for (int d = 1; d < 64; d <<= 1) s += __shfl_xor(s, d);
    if ((t & 63) == 0) red[t >> 6] = s;
    __syncthreads();
    if (t == 0) bsum[b] = red[0] + red[1] + red[2] + red[3];
}

__global__ __launch_bounds__(128) void k_scan_base(int* __restrict__ bsum,
                                                   int* __restrict__ bbase,
                                                   int* __restrict__ start) {
    if (threadIdx.x == 0) {
        int run = 0;
        for (int i = 0; i < SCB; ++i) { bbase[i] = run; run += bsum[i]; }
        start[NN] = run;   // == EE
    }
}

__global__ __launch_bounds__(256) void k_scan_fin(const int* __restrict__ cnt,
                                                  const int* __restrict__ bbase,
                                                  int* __restrict__ start) {
    __shared__ int ts[256];
    int b = blockIdx.x, t = threadIdx.x;
    int base = b * 1024 + t * 4;
    int v[4];
    int s = 0;
#pragma unroll
    for (int j = 0; j < 4; ++j) {
        int i = base + j;
        v[j] = (i < NN) ? cnt[i] : 0;
        s += v[j];
    }
    ts[t] = s;
    __syncthreads();
    for (int d = 1; d < 256; d <<= 1) {
        int add = (t >= d) ? ts[t - d] : 0;
        __syncthreads();
        ts[t] += add;
        __syncthreads();
    }
    int run = bbase[b] + ts[t] - s;   // exclusive offset for this thread
#pragma unroll
    for (int j = 0; j < 4; ++j) {
        int i = base + j;
        if (i < NN) {
            start[i] = run;
            run += v[j];
        }
    }
}

// ---------------- fill CSR records (src, norm), ATOMIC-FREE via rank ----------------

__global__ __launch_bounds__(256) void k_fill(const int* __restrict__ ei,
                                              const float* __restrict__ ew,
                                              const float* __restrict__ dinv,
                                              const int* __restrict__ start,
                                              const int* __restrict__ rank,
                                              uint2* __restrict__ csr) {
    int e = blockIdx.x * 256 + threadIdx.x;
    if (e < EE) {
        int src = ei[e];
        int dst = ei[EE + e];
        float nrm = dinv[src] * ew[e] * dinv[dst];
        int pos = start[dst] + rank[e];
        csr[pos] = make_uint2((uint)src, __float_as_uint(nrm));
    }
}

// ---------------- fused gather + conv GEMM (r17 proven version) ----------------
// 64 nodes/block, 8 waves. Phase 1: agg = dinv^2*x~ + sum norm*x~[src] -> swizzled LDS.
// Phase 2: y = x~ + agg @ W + b -> ybuf (bf16), BN1 stats. W async-staged from WTimg.

#define SWZ16(row, kb) ((((kb) ^ ((row) & 15)) << 3))

__global__ __launch_bounds__(512, 6) void k_gconv(const ushort* __restrict__ xb,
                                                  const float* __restrict__ dinv,
                                                  const int* __restrict__ start,
                                                  const uint2* __restrict__ csr,
                                                  const ushort* __restrict__ WTimg,
                                                  const float* __restrict__ b,
                                                  ushort* __restrict__ ybuf,
                                                  float* __restrict__ stats1) {
    __shared__ __align__(16) ushort xt[64 * 128];   // 16 KB agg tile (swizzled)
    __shared__ __align__(16) ushort wc[128 * 128];  // 32 KB W image
    int t = threadIdx.x;
    int row0 = blockIdx.x * 64;   // grid 1563; last block partial
    int wv = t >> 6, l = t & 63;

    // async stage W image (linear 32KB)
#pragma unroll
    for (int i = 0; i < 4; ++i) {
        int u = (t + i * 512) * 8;
        gld_lds16(WTimg + u, wc + u);
    }

    // gather 8 nodes per wave -> xt (lane handles 2 features)
    const uint* xbu = (const uint*)xb;
    for (int k = 0; k < 8; ++k) {
        int rloc = wv * 8 + k;
        int node = row0 + rloc;
        float a0 = 0.f, a1 = 0.f;
        if (node < NN) {
            int e0 = start[node], e1 = start[node + 1];
            int i = e0;
            for (; i + 8 <= e1; i += 8) {
                uint2 rr[8];
                uint hh[8];
#pragma unroll
                for (int u = 0; u < 8; ++u) rr[u] = csr[i + u];
#pragma unroll
                for (int u = 0; u < 8; ++u) hh[u] = xbu[rr[u].x * 64 + l];
#pragma unroll
                for (int u = 0; u < 8; ++u) {
                    float n = __uint_as_float(rr[u].y);
                    a0 = fmaf(n, b2f((ushort)(hh[u] & 0xFFFF)), a0);
                    a1 = fmaf(n, b2f((ushort)(hh[u] >> 16)), a1);
                }
            }
            if (i + 4 <= e1) {
                uint2 rr[4];
                uint hh[4];
#pragma unroll
                for (int u = 0; u < 4; ++u) rr[u] = csr[i + u];
#pragma unroll
                for (int u = 0; u < 4; ++u) hh[u] = xbu[rr[u].x * 64 + l];
#pragma unroll
                for (int u = 0; u < 4; ++u) {
                    float n = __uint_as_float(rr[u].y);
                    a0 = fmaf(n, b2f((ushort)(hh[u] & 0xFFFF)), a0);
                    a1 = fmaf(n, b2f((ushort)(hh[u] >> 16)), a1);
                }
                i += 4;
            }
            for (; i < e1; ++i) {
                uint2 r0 = csr[i];
                uint h0 = xbu[r0.x * 64 + l];
                float n0 = __uint_as_float(r0.y);
                a0 = fmaf(n0, b2f((ushort)(h0 & 0xFFFF)), a0);
                a1 = fmaf(n0, b2f((ushort)(h0 >> 16)), a1);
            }
            float dv = dinv[node];
            float sl = dv * dv;
            uint hs = xbu[(long)node * 64 + l];
            a0 = fmaf(sl, b2f((ushort)(hs & 0xFFFF)), a0);
            a1 = fmaf(sl, b2f((ushort)(hs >> 16)), a1);
        }
        int col = 2 * l;
        uint pv = (uint)f2b(a0) | ((uint)f2b(a1) << 16);
        *(uint*)&xt[rloc * 128 + SWZ16(rloc, col >> 3) + (col & 7)] = pv;
    }
    __syncthreads();   // xt complete; gld_lds drained -> wc ready

    int lr = l & 15, lg = l >> 4;
    int rw = wv & 3, jw = wv >> 2;
    int xrow = rw * 16 + lr;

    f32x4 z4 = {0.f, 0.f, 0.f, 0.f};
    f32x4 acc[4];
#pragma unroll
    for (int jt = 0; jt < 4; ++jt) acc[jt] = z4;

#pragma unroll
    for (int ks = 0; ks < 4; ++ks) {
        int kcol = ((ks * 4 + lg) ^ lr) << 3;
        bf16x8 qR = *(const bf16x8*)&xt[xrow * 128 + kcol];
#pragma unroll
        for (int jt = 0; jt < 4; ++jt) {
            int f = jw * 64 + jt * 16 + lr;
            bf16x8 pW = *(const bf16x8*)&wc[f * 128 + kcol];
            acc[jt] = __builtin_amdgcn_mfma_f32_16x16x32_bf16(pW, qR, acc[jt], 0, 0, 0);
        }
    }

    // epilogue: y = x~ + acc + b -> ybuf (bf16), BN1 partials
    float sj[4][4], qj[4][4];
    int r = row0 + xrow;
#pragma unroll
    for (int jt = 0; jt < 4; ++jt) {
        int jb = jw * 64 + jt * 16 + lg * 4;
        float4 bv = *(const float4*)&b[jb];
        if (r < NN) {
            ushort4 xv = *(const ushort4*)&xb[(long)r * 128 + jb];
            float z0 = b2f(xv.x) + acc[jt][0] + bv.x;
            float z1 = b2f(xv.y) + acc[jt][1] + bv.y;
            float z2 = b2f(xv.z) + acc[jt][2] + bv.z;
            float z3 = b2f(xv.w) + acc[jt][3] + bv.w;
            ushort4 o;
            o.x = f2b(z0); o.y = f2b(z1); o.z = f2b(z2); o.w = f2b(z3);
            *(ushort4*)&ybuf[(long)r * 128 + jb] = o;
            sj[jt][0] = z0; sj[jt][1] = z1; sj[jt][2] = z2; sj[jt][3] = z3;
            qj[jt][0] = z0 * z0; qj[jt][1] = z1 * z1; qj[jt][2] = z2 * z2; qj[jt][3] = z3 * z3;
        } else {
            sj[jt][0] = 0.f; sj[jt][1] = 0.f; sj[jt][2] = 0.f; sj[jt][3] = 0.f;
            qj[jt][0] = 0.f; qj[jt][1] = 0.f; qj[jt][2] = 0.f; qj[jt][3] = 0.f;
        }
    }
#pragma unroll
    for (int jt = 0; jt < 4; ++jt)
#pragma unroll
        for (int g = 0; g < 4; ++g) {
#pragma unroll
            for (int d = 1; d < 16; d <<= 1) {
                sj[jt][g] += __shfl_xor(sj[jt][g], d);
                qj[jt][g] += __shfl_xor(qj[jt][g], d);
            }
        }
    __syncthreads();   // xt reads done; reuse as reduction buffer
    float* redS = (float*)&xt[0];    // [8][128]
    float* redQ = redS + 1024;       // [8][128]
    if (lr == 0) {
#pragma unroll
        for (int jt = 0; jt < 4; ++jt)
#pragma unroll
            for (int g = 0; g < 4; ++g) {
                int j = jw * 64 + jt * 16 + lg * 4 + g;
                redS[wv * 128 + j] = sj[jt][g];
                redQ[wv * 128 + j] = qj[jt][g];
            }
    }
    __syncthreads();
    if (t < 128) {
        int h = t >> 6;   // j-half; owned by waves h*4 .. h*4+3
        float S = redS[(h * 4 + 0) * 128 + t] + redS[(h * 4 + 1) * 128 + t]
                + redS[(h * 4 + 2) * 128 + t] + redS[(h * 4 + 3) * 128 + t];
        float Q = redQ[(h * 4 + 0) * 128 + t] + redQ[(h * 4 + 1) * 128 + t]
                + redQ[(h * 4 + 2) * 128 + t] + redQ[(h * 4 + 3) * 128 + t];
        atomicAdd(&stats1[t], S);
        atomicAdd(&stats1[128 + t], Q);
    }
}

// ---------------- BN finalize ----------------

__global__ __launch_bounds__(128) void k_bn_fin(const float* __restrict__ stats,
                                                const float* __restrict__ gamma,
                                                const float* __restrict__ beta,
                                                float* __restrict__ ac) {
    int c = threadIdx.x;
    float mu = stats[c] * (1.0f / NN);
    float var = stats[128 + c] * (1.0f / NN) - mu * mu;
    float a = gamma[c] * rsqrtf(var + EPSV);
    ac[c] = a;
    ac[128 + c] = beta[c] - mu * a;
}

// ---------------- final affine: out = a * zb + c (bf16 in, fp32 out) ----------------

__global__ __launch_bounds__(256) void k_affine2(const ushort* __restrict__ zb,
                                                 const float* __restrict__ ac,
                                                 float* __restrict__ out) {
    long i = (long)blockIdx.x * 256 + threadIdx.x;   // float4 units
    int c4i = (int)(i & 31);
    float4 a = ((const float4*)ac)[c4i];
    float4 cc = ((const float4*)(ac + 128))[c4i];
    ushort4 zv = ((const ushort4*)zb)[i];
    float4 o;
    o.x = a.x * b2f(zv.x) + cc.x;
    o.y = a.y * b2f(zv.y) + cc.y;
    o.z = a.z * b2f(zv.z) + cc.z;
    o.w = a.w * b2f(zv.w) + cc.w;
    ((float4*)out)[i] = o;
}

// ---------------- fused MLP v10: async image staging + swapped GEMM1 ----------------

__global__ __launch_bounds__(512, 4) void k_mlp(const ushort* __restrict__ yb,
                                                const float* __restrict__ ac1,
                                                const ushort* __restrict__ W1img,
                                                const float* __restrict__ b1,
                                                const ushort* __restrict__ W2img,
                                                const float* __restrict__ b2,
                                                ushort* __restrict__ zb,
                                                float* __restrict__ stats2) {
    __shared__ __align__(16) ushort xt[64 * 128];   // 16 KB
    __shared__ __align__(16) ushort ht[64 * 128];   // 16 KB
    __shared__ __align__(16) ushort wc[128 * 128];  // 32 KB
    int t = threadIdx.x;
    int row0 = blockIdx.x * 64;   // grid 1563; last block partial

    // stage x1 = affine(yb) -> bf16, swizzled (1024 x 16B)
    for (int i = t; i < 1024; i += 512) {
        int r = i >> 4, kb = i & 15;
        int gr = row0 + r;
        ushort4 y0 = make_ushort4(0, 0, 0, 0), y1 = make_ushort4(0, 0, 0, 0);
        if (gr < NN) {
            long base = (long)gr * 32 + kb * 2;
            y0 = ((const ushort4*)yb)[base];
            y1 = ((const ushort4*)yb)[base + 1];
        }
        float4 a0 = ((const float4*)ac1)[kb * 2];
        float4 a1 = ((const float4*)ac1)[kb * 2 + 1];
        float4 c0 = ((const float4*)(ac1 + 128))[kb * 2];
        float4 c1 = ((const float4*)(ac1 + 128))[kb * 2 + 1];
        ushort4 o0, o1;
        o0.x = f2b(a0.x * b2f(y0.x) + c0.x);
        o0.y = f2b(a0.y * b2f(y0.y) + c0.y);
        o0.z = f2b(a0.z * b2f(y0.z) + c0.z);
        o0.w = f2b(a0.w * b2f(y0.w) + c0.w);
        o1.x = f2b(a1.x * b2f(y1.x) + c1.x);
        o1.y = f2b(a1.y * b2f(y1.y) + c1.y);
        o1.z = f2b(a1.z * b2f(y1.z) + c1.z);
        o1.w = f2b(a1.w * b2f(y1.w) + c1.w);
        ushort* dst = &xt[r * 128 + SWZ16(r, kb)];
        *(ushort4*)dst = o0;
        *(ushort4*)(dst + 4) = o1;
    }

    int wv = t >> 6, l = t & 63;
    int lr = l & 15, lg = l >> 4;
    int rw = wv & 3, jw = wv >> 2;
    int xrow = rw * 16 + lr;        // xrow & 15 == lr

    f32x4 z4 = {0.f, 0.f, 0.f, 0.f};
    f32x4 acc[4];
#pragma unroll
    for (int jt = 0; jt < 4; ++jt) acc[jt] = z4;

    for (int ch = 0; ch < 4; ++ch) {
        __syncthreads();   // wc free (prev GEMM2 done); xt staged (ch=0)
        {
            const ushort* src = W1img + ch * 16384;
#pragma unroll
            for (int i = 0; i < 4; ++i) {
                int u = (t + i * 512) * 8;
                gld_lds16(src + u, wc + u);
            }
        }
        __syncthreads();   // drains vmcnt -> wc = W1ch ready

        // GEMM1 SWAPPED: hacc[ft] holds 4 consecutive f per reg, col = xrow
        f32x4 hacc[4];
#pragma unroll
        for (int ft = 0; ft < 4; ++ft) hacc[ft] = z4;
#pragma unroll
        for (int ks = 0; ks < 4; ++ks) {
            int kcol = ((ks * 4 + lg) ^ lr) << 3;
            bf16x8 aR = *(const bf16x8*)&xt[xrow * 128 + kcol];
#pragma unroll
            for (int ft = 0; ft < 4; ++ft) {
                int f = jw * 64 + ft * 16 + lr;
                bf16x8 bW = *(const bf16x8*)&wc[f * 128 + kcol];
                hacc[ft] = __builtin_amdgcn_mfma_f32_16x16x32_bf16(bW, aR, hacc[ft], 0, 0, 0);
            }
        }
#pragma unroll
        for (int ft = 0; ft < 4; ++ft) {
            int fc = jw * 64 + ft * 16 + lg * 4;
            float4 b1v = *(const float4*)&b1[ch * 128 + fc];
            ushort4 o;
            o.x = f2b(fmaxf(hacc[ft][0] + b1v.x, 0.f));
            o.y = f2b(fmaxf(hacc[ft][1] + b1v.y, 0.f));
            o.z = f2b(fmaxf(hacc[ft][2] + b1v.z, 0.f));
            o.w = f2b(fmaxf(hacc[ft][3] + b1v.w, 0.f));
            *(ushort4*)&ht[xrow * 128 + (((fc >> 3) ^ lr) << 3) + (fc & 7)] = o;
        }
        __syncthreads();   // ht complete, wc free

        {
            const ushort* src = W2img + ch * 16384;
#pragma unroll
            for (int i = 0; i < 4; ++i) {
                int u = (t + i * 512) * 8;
                gld_lds16(src + u, wc + u);
            }
        }
        __syncthreads();   // drains vmcnt -> wc = W2ch ready

        // GEMM2 swapped: acc(j x r) += W2c-rows x ht-rows
#pragma unroll
        for (int ks = 0; ks < 4; ++ks) {
            int kcol = ((ks * 4 + lg) ^ lr) << 3;
            bf16x8 qR = *(const bf16x8*)&ht[xrow * 128 + kcol];
#pragma unroll
            for (int jt = 0; jt < 4; ++jt) {
                int j = jw * 64 + jt * 16 + lr;
                bf16x8 pW = *(const bf16x8*)&wc[j * 128 + kcol];
                acc[jt] = __builtin_amdgcn_mfma_f32_16x16x32_bf16(pW, qR, acc[jt], 0, 0, 0);
            }
        }
    }

    // epilogue: z = x1 + x2 + b2 -> zb (bf16), BN2 partials
    float sj[4][4], qj[4][4];
    int r = row0 + xrow;
#pragma unroll
    for (int jt = 0; jt < 4; ++jt) {
        int jb = jw * 64 + jt * 16 + lg * 4;
        float4 b2v = *(const float4*)&b2[jb];
        int kbj = jb >> 3, wj = jb & 7;
        ushort4 xv = *(const ushort4*)&xt[xrow * 128 + ((kbj ^ lr) << 3) + wj];
        float z0 = b2f(xv.x) + acc[jt][0] + b2v.x;
        float z1 = b2f(xv.y) + acc[jt][1] + b2v.y;
        float z2 = b2f(xv.z) + acc[jt][2] + b2v.z;
        float z3 = b2f(xv.w) + acc[jt][3] + b2v.w;
        if (r < NN) {
            ushort4 o;
            o.x = f2b(z0); o.y = f2b(z1); o.z = f2b(z2); o.w = f2b(z3);
            *(ushort4*)&zb[(long)r * 128 + jb] = o;
            sj[jt][0] = z0; sj[jt][1] = z1; sj[jt][2] = z2; sj[jt][3] = z3;
            qj[jt][0] = z0 * z0; qj[jt][1] = z1 * z1; qj[jt][2] = z2 * z2; qj[jt][3] = z3 * z3;
        } else {
            sj[jt][0] = 0.f; sj[jt][1] = 0.f; sj[jt][2] = 0.f; sj[jt][3] = 0.f;
            qj[jt][0] = 0.f; qj[jt][1] = 0.f; qj[jt][2] = 0.f; qj[jt][3] = 0.f;
        }
    }
#pragma unroll
    for (int jt = 0; jt < 4; ++jt)
#pragma unroll
        for (int g = 0; g < 4; ++g) {
#pragma unroll
            for (int d = 1; d < 16; d <<= 1) {
                sj[jt][g] += __shfl_xor(sj[jt][g], d);
                qj[jt][g] += __shfl_xor(qj[jt][g], d);
            }
        }
    __syncthreads();   // ht reads done; reuse as reduction buffer
    float* redS = (float*)&ht[0];    // [8][128]
    float* redQ = redS + 1024;       // [8][128]
    if (lr == 0) {
#pragma unroll
        for (int jt = 0; jt < 4; ++jt)
#pragma unroll
            for (int g = 0; g < 4; ++g) {
                int j = jw * 64 + jt * 16 + lg * 4 + g;
                redS[wv * 128 + j] = sj[jt][g];
                redQ[wv * 128 + j] = qj[jt][g];
            }
    }
    __syncthreads();
    if (t < 128) {
        int h = t >> 6;   // j-half; owned by waves h*4 .. h*4+3
        float S = redS[(h * 4 + 0) * 128 + t] + redS[(h * 4 + 1) * 128 + t]
                + redS[(h * 4 + 2) * 128 + t] + redS[(h * 4 + 3) * 128 + t];
        float Q = redQ[(h * 4 + 0) * 128 + t] + redQ[(h * 4 + 1) * 128 + t]
                + redQ[(h * 4 + 2) * 128 + t] + redQ[(h * 4 + 3) * 128 + t];
        atomicAdd(&stats2[t], S);
        atomicAdd(&stats2[128 + t], Q);
    }
}

// ---------------- launch ----------------

extern "C" void kernel_launch(void* const* d_in, const int* in_sizes, int n_in,
                              void* d_out, int out_size, void* d_ws, size_t ws_size,
                              hipStream_t stream) {
    const float* x     = (const float*)d_in[0];
    const int*   ei    = (const int*)d_in[1];
    const float* ew    = (const float*)d_in[2];
    const float* W     = (const float*)d_in[3];
    const float* b     = (const float*)d_in[4];
    const float* gamma = (const float*)d_in[5];
    const float* beta  = (const float*)d_in[6];
    const float* W1    = (const float*)d_in[7];
    const float* b1    = (const float*)d_in[8];
    const float* W2    = (const float*)d_in[9];
    const float* b2    = (const float*)d_in[10];
    float* out = (float*)d_out;
    float* ws  = (float*)d_ws;

    ull*   pk     = (ull*)ws;                        // NN (8B each)
    float* dinv   = ws + 2 * NN;                     // NN
    float* stats1 = ws + 3 * NN;                     // 256
    float* ac1    = stats1 + 256;                    // 256
    float* stats2 = ac1 + 256;                       // 256
    float* ac2    = stats2 + 256;                    // 256
    ushort* xb    = (ushort*)(ws + 3 * NN + 1024);   // NN*128 bf16
    ushort* WTimg = xb + (long)NN * 128;             // 16384
    ushort* W1img = WTimg + 16384;                   // 65536
    ushort* W2img = W1img + 65536;                   // 65536
    float*  fend  = ws + 3 * NN + 1024 + (long)NN * 64 + 73728;
    int*   cnt    = (int*)fend;                      // NN
    int*   start  = cnt + NN;                        // NN+1
    int*   bsum   = start + NN + 1;                  // SCB
    int*   bbase  = bsum + SCB;                      // SCB
    uint2* csr    = (uint2*)(((uintptr_t)(bbase + SCB) + 7) & ~(uintptr_t)7);  // EE records
    ushort* ybuf  = (ushort*)(csr + EE);             // NN*128 bf16 (y)
    int*   rank   = (int*)ybuf;                      // EE ints; lifetime before ybuf (disjoint)
    ushort* zb    = xb;                              // xb dead after k_gconv; reuse for bf16 z

    int nb = (NN + 63) / 64;   // 1563

    k_init<<<(NN + 255) / 256, 256, 0, stream>>>(pk, stats1, stats2);
    k_pre<<<MIXB + 576, 256, 0, stream>>>(ei, ew, pk, rank, x, xb, W, W1, W2, WTimg, W1img, W2img);
    k_scan_part<<<SCB, 256, 0, stream>>>(pk, cnt, dinv, bsum);
    k_scan_base<<<1, 128, 0, stream>>>(bsum, bbase, start);
    k_scan_fin<<<SCB, 256, 0, stream>>>(cnt, bbase, start);
    k_fill<<<EE / 256, 256, 0, stream>>>(ei, ew, dinv, start, rank, csr);
    k_gconv<<<nb, 512, 0, stream>>>(xb, dinv, start, csr, WTimg, b, ybuf, stats1);
    k_bn_fin<<<1, 128, 0, stream>>>(stats1, gamma, beta, ac1);
    k_mlp<<<nb, 512, 0, stream>>>(ybuf, ac1, W1img, b1, W2img, b2, zb, stats2);
    k_bn_fin<<<1, 128, 0, stream>>>(stats2, gamma, beta, ac2);
    k_affine2<<<(NN * 32) / 256, 256, 0, stream>>>(zb, ac2, out);
}